// Round 14
// baseline (522.495 us; speedup 1.0000x reference)
//
#include <hip/hip_runtime.h>

// Problem constants (from reference)
#define BATCH 2048
#define T 512
#define NF 10
#define HID 30
#define S3T 1536          // 3*T sequence length after reshape/transpose
#define FEAT_PER_B 15360  // 10*1536 floats per batch element
// Workspace: BATCH * FEAT_PER_B * 4 = 125,829,120 bytes
// Layout: xpair[b][p][s][e] (p<5, s<1536, e<2) = x[b][s][2p+e] — one dwordx4
// at (b,p,2*ch) = d-pair (2p,2p+1) for steps 2ch,2ch+1 -> natural v2f halves.

typedef float v2f __attribute__((ext_vector_type(2)));
typedef float v4f __attribute__((ext_vector_type(4)));  // clang vector: legal
                                                        // for nontemporal b.i.

#define LOG2E 1.44269504088896f

__device__ __forceinline__ float fexp(float x) {
    return __builtin_amdgcn_exp2f(x * LOG2E);   // v_exp_f32
}
__device__ __forceinline__ float frcp(float x) {
    return __builtin_amdgcn_rcpf(x);            // v_rcp_f32
}

// Packed fp32 FMA. R12 evidence: forcing this via asm == letting LLVM emit it
// (gru 430 vs 420us) -> pk WAS already formed. Kept because it pins codegen.
// NOTE: v_pk_fma_f32 is HALF-RATE per lane on gfx950 (fp32 peak 157 TF = 1
// scalar FMA/lane/cyc; pk = 4 cyc/wave64) -> 60 pk/step = 240 cyc is the
// FLOP floor of this mapping, not reducible by issue tricks.
__device__ __forceinline__ v2f pk_fma(v2f a, v2f b, v2f c) {
    v2f d;
    asm("v_pk_fma_f32 %0, %1, %2, %3" : "=v"(d) : "v"(a), "v"(b), "v"(c));
    return d;
}

// Kernel 1: materialize xpair, one v4f per thread (2 steps x 1 d-pair).
// [R11: 107 -> ~79us vs scalar stores] R13: nontemporal stores — the 126 MB
// pure write-stream ran at ~1.5 TB/s effective, consistent with RFO/write-
// allocate; NT store skips the read-for-ownership. (R13 compile fix: the
// builtin requires a clang ext_vector type, not HIP's float4 class.)
__global__ void feat_kernel(const int* __restrict__ atom_i,
                            const int* __restrict__ atom_j,
                            const float* __restrict__ dist,
                            const float* __restrict__ emb,
                            v4f* __restrict__ xpair4) {
    int g = blockIdx.x * blockDim.x + threadIdx.x;
    const int total4 = BATCH * (FEAT_PER_B / 4);  // 7,864,320
    if (g >= total4) return;
    int b  = g / 3840;
    int r4 = g - b * 3840;
    int p  = r4 / 768;         // d-pair index
    int c  = r4 - p * 768;     // v4f index within the pair stream
    float vv[4];
#pragma unroll
    for (int kx = 0; kx < 4; ++kx) {
        int s = 2 * c + (kx >> 1);
        int e = kx & 1;
        int f = (2 * p + e) * S3T + s;   // flat index into featflat_b
        int t = f / 30;
        int cc = f - t * 30;
        int bt = b * T + t;
        float v;
        if (cc < 10) {
            int ai = atom_i[bt];
            v = (ai != 0) ? emb[ai * NF + cc] : 0.0f;
        } else if (cc < 20) {
            int aj = atom_j[bt];
            v = (aj != 0) ? emb[aj * NF + (cc - 10)] : 0.0f;
        } else {
            int ai = atom_i[bt];
            float dd = dist[bt];
            float ctr = (float)(cc - 19) * 0.7f;
            float df = ctr - dd;
            v = (ai != 0) ? fexp(-df * df) : 0.0f;
        }
        vv[kx] = v;
    }
    v4f o = (v4f){vv[0], vv[1], vv[2], vv[3]};
    __builtin_nontemporal_store(o, &xpair4[g]);
}

// One GRU step, reads hbuf[PAR], writes hbuf[PAR^1].
// R13 ordering (stall cover): (1) hj loads issued FIRST; (2) the 15 ih
// pk-FMAs + all bias seeds run before ANY hj consumer (xc is 2-steps
// prefetched, fully independent -> ~60+ cyc of legal cover for the ~120-cyc
// ds_read latency; R12 consumed hj[0] in the first post-load inst); (3) hh
// dots last; (4) both sigmoids' exp2 issued back-to-back before the rcps.
// Trailing wavefront fence replaces __syncthreads [R10: 576->420us].
#define STEP(PAR, XQ, IDX)                                                   \
    {                                                                        \
        const float4* hv = (const float4*)&hbuf[PAR][half * 32];             \
        v2f hj[16];                                                          \
        _Pragma("unroll")                                                    \
        for (int qq = 0; qq < 8; ++qq) {                                     \
            float4 tq = hv[qq];                                              \
            __builtin_memcpy(&hj[2 * qq], &tq, 16);                          \
        }                                                                    \
        v2f xc[5];                                                           \
        _Pragma("unroll")                                                    \
        for (int pp = 0; pp < 5; ++pp)                                       \
            __builtin_memcpy(&xc[pp], ((const char*)&XQ[pp]) + 8 * (IDX), 8);\
        v2f ar2 = pk_fma(wir[0], xc[0], brv);                                \
        v2f az2 = pk_fma(wiz[0], xc[0], bzv);                                \
        v2f ai2 = pk_fma(win[0], xc[0], biv);                                \
        _Pragma("unroll")                                                    \
        for (int d2 = 1; d2 < 5; ++d2) {                                     \
            ar2 = pk_fma(wir[d2], xc[d2], ar2);                              \
            az2 = pk_fma(wiz[d2], xc[d2], az2);                              \
            ai2 = pk_fma(win[d2], xc[d2], ai2);                              \
        }                                                                    \
        v2f ah2 = pk_fma(whn[0], hj[0], bhv);                                \
        _Pragma("unroll")                                                    \
        for (int j = 0; j < 15; ++j) {                                       \
            ar2 = pk_fma(whr[j], hj[j], ar2);                                \
            az2 = pk_fma(whz[j], hj[j], az2);                                \
            if (j) ah2 = pk_fma(whn[j], hj[j], ah2);                         \
        }                                                                    \
        float ar = ar2.x + ar2.y, az = az2.x + az2.y;                        \
        float ah = ah2.x + ah2.y, ai = ai2.x + ai2.y;                        \
        float er = __builtin_amdgcn_exp2f(ar);                               \
        float ez = __builtin_amdgcn_exp2f(az);                               \
        float rg = frcp(1.0f + er);                                          \
        float zg = frcp(1.0f + ez);                                          \
        float ng =                                                           \
            2.0f * frcp(1.0f + __builtin_amdgcn_exp2f(ai + rg * ah)) - 1.0f; \
        h = ng + zg * (h - ng);                                              \
        hbuf[(PAR) ^ 1][half * 32 + k] = h;                                  \
        __builtin_amdgcn_fence(__ATOMIC_ACQ_REL, "wavefront");               \
    }

// Kernel 2: GRU recurrence — full-dot mapping (R9/R10 winner), 2 batches per
// wave, 1024 single-wave blocks. Lane k (k<30) computes the complete gates
// for unit k of its half's batch (lanes 0-31 batch 2*blk, 32-61 2*blk+1).
// amdgpu_waves_per_eu(1,1) [R6/R9]: pressure target 512 regs so the ~120
// weight regs stay ARCH-resident (tighter ceilings AGPR-bounce them).
__attribute__((amdgpu_waves_per_eu(1, 1)))
__global__ void __launch_bounds__(64)
gru_kernel(const float* __restrict__ xpair,
           const float* __restrict__ W_ih,   // [90,10]
           const float* __restrict__ W_hh,   // [90,30]
           const float* __restrict__ b_ih,   // [90]
           const float* __restrict__ b_hh,   // [90]
           const float* __restrict__ W_out,  // [1,30]
           const float* __restrict__ b_out,  // [1]
           float* __restrict__ out) {
    // Double-buffered h: [buf][half*32 + k]; slots 30,31/62,63 written by
    // k=30,31 lanes but never read (hj pair 15 is loaded but unused).
    __shared__ __align__(16) float hbuf[2][64];
    const int lane = threadIdx.x;
    const int half = lane >> 5;
    const int k    = lane & 31;
    const bool active = (k < HID);
    const int kk = active ? k : (HID - 1);
    const int b = blockIdx.x * 2 + half;

    const float SRZ = -LOG2E;          // sigmoid(x) = rcp(1+exp2(-L x))
    const float SN  = -2.0f * LOG2E;   // tanh(u) = 2 rcp(1+exp2(-2L u)) - 1

    // Full-row hh weights: 15 v2f (j-pairs) per gate, log2e-prescaled.
    v2f whr[15], whz[15], whn[15];
    {
        const float2* Rr = (const float2*)&W_hh[(0 * HID + kk) * HID];
        const float2* Rz = (const float2*)&W_hh[(1 * HID + kk) * HID];
        const float2* Rn = (const float2*)&W_hh[(2 * HID + kk) * HID];
#pragma unroll
        for (int j = 0; j < 15; ++j) {
            float2 tr = Rr[j], tz = Rz[j], tn = Rn[j];
            whr[j] = (v2f){tr.x * SRZ, tr.y * SRZ};
            whz[j] = (v2f){tz.x * SRZ, tz.y * SRZ};
            whn[j] = (v2f){tn.x * SN,  tn.y * SN};
        }
    }
    // Full-row ih weights: 5 v2f per gate (d-pairs match xpair layout).
    v2f wir[5], wiz[5], win[5];
    {
        const float2* Rr = (const float2*)&W_ih[(0 * HID + kk) * NF];
        const float2* Rz = (const float2*)&W_ih[(1 * HID + kk) * NF];
        const float2* Rn = (const float2*)&W_ih[(2 * HID + kk) * NF];
#pragma unroll
        for (int d = 0; d < 5; ++d) {
            float2 tr = Rr[d], tz = Rz[d], tn = Rn[d];
            wir[d] = (v2f){tr.x * SRZ, tr.y * SRZ};
            wiz[d] = (v2f){tz.x * SRZ, tz.y * SRZ};
            win[d] = (v2f){tn.x * SN,  tn.y * SN};
        }
    }
    // Biases (prescaled), folded into the first ih pk-fma of each dot.
    const v2f brv = (v2f){SRZ * (b_ih[0 * HID + kk] + b_hh[0 * HID + kk]), 0.0f};
    const v2f bzv = (v2f){SRZ * (b_ih[1 * HID + kk] + b_hh[1 * HID + kk]), 0.0f};
    const v2f biv = (v2f){SN * b_ih[2 * HID + kk], 0.0f};  // n biases stay split:
    const v2f bhv = (v2f){SN * b_hh[2 * HID + kk], 0.0f};  // n uses ai + rg*ah

    // 5 chunk base pointers: xa[p][ch] = d-pair (2p,2p+1), steps 2ch,2ch+1
    const float* xb = xpair + (long)b * FEAT_PER_B;
    const float4* xa[5];
#pragma unroll
    for (int p = 0; p < 5; ++p) xa[p] = (const float4*)(xb + p * 3072);

    hbuf[0][lane] = 0.0f;
    hbuf[1][lane] = 0.0f;
    __builtin_amdgcn_fence(__ATOMIC_ACQ_REL, "wavefront");

    float h = 0.0f;
    float4 xq0[5], xq1[5];
#pragma unroll
    for (int p = 0; p < 5; ++p) xq0[p] = xa[p][0];

    // 768 chunks of 2 steps, in pairs for compile-time buffer parity
    for (int c2 = 0; c2 < 768; c2 += 2) {
#pragma unroll
        for (int p = 0; p < 5; ++p) xq1[p] = xa[p][c2 + 1];
        STEP(0, xq0, 0);   // step 2*c2
        STEP(1, xq0, 1);   // step 2*c2+1
        const int cn = (c2 + 2 < 768) ? (c2 + 2) : 767;  // clamp final OOB
#pragma unroll
        for (int p = 0; p < 5; ++p) xq0[p] = xa[p][cn];
        STEP(0, xq1, 0);   // step 2*c2+2
        STEP(1, xq1, 1);   // step 2*c2+3
    }

    // out[b] = relu(h . W_out + b_out), reduced within each 32-lane half
    float v = active ? h * W_out[kk] : 0.0f;
#pragma unroll
    for (int off = 16; off; off >>= 1) v += __shfl_xor(v, off, 32);
    if (k == 0) {
        float o = v + b_out[0];
        out[b] = o > 0.0f ? o : 0.0f;
    }
}

extern "C" void kernel_launch(void* const* d_in, const int* in_sizes, int n_in,
                              void* d_out, int out_size, void* d_ws, size_t ws_size,
                              hipStream_t stream) {
    const int* atom_i   = (const int*)d_in[0];
    const int* atom_j   = (const int*)d_in[1];
    const float* dist   = (const float*)d_in[2];
    const float* emb    = (const float*)d_in[3];
    const float* W_ih   = (const float*)d_in[4];
    const float* W_hh   = (const float*)d_in[5];
    const float* b_ih   = (const float*)d_in[6];
    const float* b_hh   = (const float*)d_in[7];
    const float* W_out  = (const float*)d_in[8];
    const float* b_out  = (const float*)d_in[9];
    float* out = (float*)d_out;
    float* xpair = (float*)d_ws;

    const int total4 = BATCH * (FEAT_PER_B / 4);
    const int threads = 256;
    const int blocks = (total4 + threads - 1) / threads;
    feat_kernel<<<blocks, threads, 0, stream>>>(atom_i, atom_j, dist, emb,
                                                (v4f*)xpair);
    gru_kernel<<<BATCH / 2, 64, 0, stream>>>(xpair, W_ih, W_hh, b_ih, b_hh,
                                             W_out, b_out, out);
}

// Round 15
// 456.754 us; speedup vs baseline: 1.1439x; 1.1439x over previous
//
#include <hip/hip_runtime.h>

// Problem constants (from reference)
#define BATCH 2048
#define T 512
#define NF 10
#define HID 30
#define S3T 1536          // 3*T sequence length after reshape/transpose
#define FEAT_PER_B 15360  // 10*1536 floats per batch element
// Workspace: BATCH * FEAT_PER_B * 4 = 125,829,120 bytes
// Layout: xpair[b][p][s][e] (p<5, s<1536, e<2) = x[b][s][2p+e] — one dwordx4
// at (b,p,2*ch) = d-pair (2p,2p+1) for steps 2ch,2ch+1 -> natural v2f halves.

typedef float v2f __attribute__((ext_vector_type(2)));

#define LOG2E 1.44269504088896f

__device__ __forceinline__ float fexp(float x) {
    return __builtin_amdgcn_exp2f(x * LOG2E);   // v_exp_f32
}
__device__ __forceinline__ float frcp(float x) {
    return __builtin_amdgcn_rcpf(x);            // v_rcp_f32
}

// Packed fp32 FMA. R12: forcing via asm == compiler output (pk WAS formed);
// kept to pin codegen. v_pk_fma_f32 is half-rate per lane on gfx950 -> 60
// pk/step = 240 cyc is this mapping's FLOP floor.
__device__ __forceinline__ v2f pk_fma(v2f a, v2f b, v2f c) {
    v2f d;
    asm("v_pk_fma_f32 %0, %1, %2, %3" : "=v"(d) : "v"(a), "v"(b), "v"(c));
    return d;
}

// Kernel 1 (R15 rewrite): transpose-through-LDS.
// R10-R14 evidence: flat-indexed version stuck at ~89us (1.56 TB/s) with
// issue est ~15us -> bound by per-element divergent 3-way branch (exec-mask
// serialization, 3 gather paths) and scattered emb gathers. New shape:
// one block per batch element b, one thread per t (512): load atom_i/atom_j/
// dist ONCE (coalesced), compute the 30-vector straight-line (no divergence,
// emb L1-resident), stage in LDS at stride 31 (conflict-free), then phase 2
// emits the xpair layout as fully-coalesced float4 stores.
__global__ void __launch_bounds__(512)
feat_kernel(const int* __restrict__ atom_i,
            const int* __restrict__ atom_j,
            const float* __restrict__ dist,
            const float* __restrict__ emb,
            float4* __restrict__ xpair4) {
    // featflat staging, padded: slot(t,c) = t*31 + c  (stride 31 coprime 32)
    __shared__ float lf[512 * 31 + 30];   // 63,608 B
    const int b = blockIdx.x;
    const int t = threadIdx.x;

    // Phase 1: compute feat[t][0..29]
    {
        const int bt = b * T + t;
        const int ai = atom_i[bt];
        const int aj = atom_j[bt];
        const float dd = dist[bt];
        const float mi = (ai != 0) ? 1.0f : 0.0f;
        const float mj = (aj != 0) ? 1.0f : 0.0f;
        const float* ei = &emb[ai * NF];
        const float* ej = &emb[aj * NF];
        float* row = &lf[t * 31];
#pragma unroll
        for (int c = 0; c < NF; ++c) row[c] = mi * ei[c];
#pragma unroll
        for (int c = 0; c < NF; ++c) row[10 + c] = mj * ej[c];
#pragma unroll
        for (int c = 0; c < NF; ++c) {
            float ctr = (float)(c + 1) * 0.7f;
            float df = ctr - dd;
            row[20 + c] = mi * fexp(-df * df);
        }
    }
    __syncthreads();

    // Phase 2: coalesced writeout in xpair order.
    // float4 index o in [0,3840): p = o/768, c4 = o%768; element kx:
    // s = 2*c4 + (kx>>1), e = kx&1, f = (2p+e)*1536 + s; value = lf-slot(f).
    float4* ob = xpair4 + (long)b * (FEAT_PER_B / 4);
    for (int o = t; o < FEAT_PER_B / 4; o += 512) {
        unsigned p  = (unsigned)o / 768u;
        unsigned c4 = (unsigned)o - p * 768u;
        float vv[4];
#pragma unroll
        for (int kx = 0; kx < 4; ++kx) {
            unsigned s = 2u * c4 + (unsigned)(kx >> 1);
            unsigned e = (unsigned)(kx & 1);
            unsigned f = (2u * p + e) * 1536u + s;
            unsigned tt = f / 30u;            // compiler -> magic mul
            unsigned cc = f - tt * 30u;
            vv[kx] = lf[tt * 31u + cc];
        }
        ob[o] = make_float4(vv[0], vv[1], vv[2], vv[3]);
    }
}

// One GRU step, reads hbuf[PAR], writes hbuf[PAR^1]. [R13/R14: ordering is
// scheduler-neutral; kept for clarity.] Trailing wavefront fence replaces
// __syncthreads [R10: 576->420us] — zero-cost compiler ordering only.
#define STEP(PAR, XQ, IDX)                                                   \
    {                                                                        \
        const float4* hv = (const float4*)&hbuf[PAR][half * 32];             \
        v2f hj[16];                                                          \
        _Pragma("unroll")                                                    \
        for (int qq = 0; qq < 8; ++qq) {                                     \
            float4 tq = hv[qq];                                              \
            __builtin_memcpy(&hj[2 * qq], &tq, 16);                          \
        }                                                                    \
        v2f xc[5];                                                           \
        _Pragma("unroll")                                                    \
        for (int pp = 0; pp < 5; ++pp)                                       \
            __builtin_memcpy(&xc[pp], ((const char*)&XQ[pp]) + 8 * (IDX), 8);\
        v2f ar2 = pk_fma(wir[0], xc[0], brv);                                \
        v2f az2 = pk_fma(wiz[0], xc[0], bzv);                                \
        v2f ai2 = pk_fma(win[0], xc[0], biv);                                \
        _Pragma("unroll")                                                    \
        for (int d2 = 1; d2 < 5; ++d2) {                                     \
            ar2 = pk_fma(wir[d2], xc[d2], ar2);                              \
            az2 = pk_fma(wiz[d2], xc[d2], az2);                              \
            ai2 = pk_fma(win[d2], xc[d2], ai2);                              \
        }                                                                    \
        v2f ah2 = pk_fma(whn[0], hj[0], bhv);                                \
        _Pragma("unroll")                                                    \
        for (int j = 0; j < 15; ++j) {                                       \
            ar2 = pk_fma(whr[j], hj[j], ar2);                                \
            az2 = pk_fma(whz[j], hj[j], az2);                                \
            if (j) ah2 = pk_fma(whn[j], hj[j], ah2);                         \
        }                                                                    \
        float ar = ar2.x + ar2.y, az = az2.x + az2.y;                        \
        float ah = ah2.x + ah2.y, ai = ai2.x + ai2.y;                        \
        float er = __builtin_amdgcn_exp2f(ar);                               \
        float ez = __builtin_amdgcn_exp2f(az);                               \
        float rg = frcp(1.0f + er);                                          \
        float zg = frcp(1.0f + ez);                                          \
        float ng =                                                           \
            2.0f * frcp(1.0f + __builtin_amdgcn_exp2f(ai + rg * ah)) - 1.0f; \
        h = ng + zg * (h - ng);                                              \
        hbuf[(PAR) ^ 1][half * 32 + k] = h;                                  \
        __builtin_amdgcn_fence(__ATOMIC_ACQ_REL, "wavefront");               \
    }

// Kernel 2: GRU recurrence — full-dot mapping (R9/R10 winner), 2 batches per
// wave, 1024 single-wave blocks. Lane k (k<30) computes the complete gates
// for unit k of its half's batch (lanes 0-31 batch 2*blk, 32-61 2*blk+1).
// amdgpu_waves_per_eu(1,1) [R6/R9]: pressure target 512 regs so the ~120
// weight regs stay ARCH-resident (tighter ceilings AGPR-bounce them).
__attribute__((amdgpu_waves_per_eu(1, 1)))
__global__ void __launch_bounds__(64)
gru_kernel(const float* __restrict__ xpair,
           const float* __restrict__ W_ih,   // [90,10]
           const float* __restrict__ W_hh,   // [90,30]
           const float* __restrict__ b_ih,   // [90]
           const float* __restrict__ b_hh,   // [90]
           const float* __restrict__ W_out,  // [1,30]
           const float* __restrict__ b_out,  // [1]
           float* __restrict__ out) {
    // Double-buffered h: [buf][half*32 + k]; slots 30,31/62,63 written by
    // k=30,31 lanes but never read (hj pair 15 is loaded but unused).
    __shared__ __align__(16) float hbuf[2][64];
    const int lane = threadIdx.x;
    const int half = lane >> 5;
    const int k    = lane & 31;
    const bool active = (k < HID);
    const int kk = active ? k : (HID - 1);
    const int b = blockIdx.x * 2 + half;

    const float SRZ = -LOG2E;          // sigmoid(x) = rcp(1+exp2(-L x))
    const float SN  = -2.0f * LOG2E;   // tanh(u) = 2 rcp(1+exp2(-2L u)) - 1

    // Full-row hh weights: 15 v2f (j-pairs) per gate, log2e-prescaled.
    v2f whr[15], whz[15], whn[15];
    {
        const float2* Rr = (const float2*)&W_hh[(0 * HID + kk) * HID];
        const float2* Rz = (const float2*)&W_hh[(1 * HID + kk) * HID];
        const float2* Rn = (const float2*)&W_hh[(2 * HID + kk) * HID];
#pragma unroll
        for (int j = 0; j < 15; ++j) {
            float2 tr = Rr[j], tz = Rz[j], tn = Rn[j];
            whr[j] = (v2f){tr.x * SRZ, tr.y * SRZ};
            whz[j] = (v2f){tz.x * SRZ, tz.y * SRZ};
            whn[j] = (v2f){tn.x * SN,  tn.y * SN};
        }
    }
    // Full-row ih weights: 5 v2f per gate (d-pairs match xpair layout).
    v2f wir[5], wiz[5], win[5];
    {
        const float2* Rr = (const float2*)&W_ih[(0 * HID + kk) * NF];
        const float2* Rz = (const float2*)&W_ih[(1 * HID + kk) * NF];
        const float2* Rn = (const float2*)&W_ih[(2 * HID + kk) * NF];
#pragma unroll
        for (int d = 0; d < 5; ++d) {
            float2 tr = Rr[d], tz = Rz[d], tn = Rn[d];
            wir[d] = (v2f){tr.x * SRZ, tr.y * SRZ};
            wiz[d] = (v2f){tz.x * SRZ, tz.y * SRZ};
            win[d] = (v2f){tn.x * SN,  tn.y * SN};
        }
    }
    // Biases (prescaled), folded into the first ih pk-fma of each dot.
    const v2f brv = (v2f){SRZ * (b_ih[0 * HID + kk] + b_hh[0 * HID + kk]), 0.0f};
    const v2f bzv = (v2f){SRZ * (b_ih[1 * HID + kk] + b_hh[1 * HID + kk]), 0.0f};
    const v2f biv = (v2f){SN * b_ih[2 * HID + kk], 0.0f};  // n biases stay split:
    const v2f bhv = (v2f){SN * b_hh[2 * HID + kk], 0.0f};  // n uses ai + rg*ah

    // 5 chunk base pointers: xa[p][ch] = d-pair (2p,2p+1), steps 2ch,2ch+1
    const float* xb = xpair + (long)b * FEAT_PER_B;
    const float4* xa[5];
#pragma unroll
    for (int p = 0; p < 5; ++p) xa[p] = (const float4*)(xb + p * 3072);

    hbuf[0][lane] = 0.0f;
    hbuf[1][lane] = 0.0f;
    __builtin_amdgcn_fence(__ATOMIC_ACQ_REL, "wavefront");

    float h = 0.0f;
    float4 xq0[5], xq1[5];
#pragma unroll
    for (int p = 0; p < 5; ++p) xq0[p] = xa[p][0];

    // 768 chunks of 2 steps, in pairs for compile-time buffer parity
    for (int c2 = 0; c2 < 768; c2 += 2) {
#pragma unroll
        for (int p = 0; p < 5; ++p) xq1[p] = xa[p][c2 + 1];
        STEP(0, xq0, 0);   // step 2*c2
        STEP(1, xq0, 1);   // step 2*c2+1
        const int cn = (c2 + 2 < 768) ? (c2 + 2) : 767;  // clamp final OOB
#pragma unroll
        for (int p = 0; p < 5; ++p) xq0[p] = xa[p][cn];
        STEP(0, xq1, 0);   // step 2*c2+2
        STEP(1, xq1, 1);   // step 2*c2+3
    }

    // out[b] = relu(h . W_out + b_out), reduced within each 32-lane half
    float v = active ? h * W_out[kk] : 0.0f;
#pragma unroll
    for (int off = 16; off; off >>= 1) v += __shfl_xor(v, off, 32);
    if (k == 0) {
        float o = v + b_out[0];
        out[b] = o > 0.0f ? o : 0.0f;
    }
}

extern "C" void kernel_launch(void* const* d_in, const int* in_sizes, int n_in,
                              void* d_out, int out_size, void* d_ws, size_t ws_size,
                              hipStream_t stream) {
    const int* atom_i   = (const int*)d_in[0];
    const int* atom_j   = (const int*)d_in[1];
    const float* dist   = (const float*)d_in[2];
    const float* emb    = (const float*)d_in[3];
    const float* W_ih   = (const float*)d_in[4];
    const float* W_hh   = (const float*)d_in[5];
    const float* b_ih   = (const float*)d_in[6];
    const float* b_hh   = (const float*)d_in[7];
    const float* W_out  = (const float*)d_in[8];
    const float* b_out  = (const float*)d_in[9];
    float* out = (float*)d_out;
    float* xpair = (float*)d_ws;

    feat_kernel<<<BATCH, 512, 0, stream>>>(atom_i, atom_j, dist, emb,
                                           (float4*)xpair);
    gru_kernel<<<BATCH / 2, 64, 0, stream>>>(xpair, W_ih, W_hh, b_ih, b_hh,
                                             W_out, b_out, out);
}

// Round 16
// 402.236 us; speedup vs baseline: 1.2990x; 1.1355x over previous
//
#include <hip/hip_runtime.h>

// Problem constants (from reference)
#define BATCH 2048
#define T 512
#define NF 10
#define HID 30
#define S3T 1536          // 3*T sequence length after reshape/transpose
#define FEAT_PER_B 15360  // 10*1536 features per batch element
// Workspace: BATCH * FEAT_PER_B * 2 = 62,914,560 bytes (f16 xpair)
// Layout: xpair[b][p][s][e] (p<5, s<1536, e<2) = f16 x[b][s][2p+e].
// One uint4 (16B) at stream p, chunk c = d-pair (2p,2p+1) for steps 4c..4c+3.

typedef float  v2f __attribute__((ext_vector_type(2)));
typedef _Float16 v2h __attribute__((ext_vector_type(2)));

#define LOG2E 1.44269504088896f

__device__ __forceinline__ float fexp(float x) {
    return __builtin_amdgcn_exp2f(x * LOG2E);   // v_exp_f32
}
__device__ __forceinline__ float frcp(float x) {
    return __builtin_amdgcn_rcpf(x);            // v_rcp_f32
}

// Kernel 1: transpose-through-LDS [R15: 89 -> ~19us], now emitting f16.
// Phase 1: one thread per t, straight-line 30-vector (no divergence, emb
// L1-resident), staged at stride 31 (conflict-free). Phase 2: coalesced
// uint4 stores (8 f16) in xpair order; f16 convert is RNE.
__global__ void __launch_bounds__(512)
feat_kernel(const int* __restrict__ atom_i,
            const int* __restrict__ atom_j,
            const float* __restrict__ dist,
            const float* __restrict__ emb,
            uint4* __restrict__ xpair8) {
    __shared__ float lf[512 * 31 + 30];   // slot(t,c) = t*31 + c
    const int b = blockIdx.x;
    const int t = threadIdx.x;

    {
        const int bt = b * T + t;
        const int ai = atom_i[bt];
        const int aj = atom_j[bt];
        const float dd = dist[bt];
        const float mi = (ai != 0) ? 1.0f : 0.0f;
        const float mj = (aj != 0) ? 1.0f : 0.0f;
        const float* ei = &emb[ai * NF];
        const float* ej = &emb[aj * NF];
        float* row = &lf[t * 31];
#pragma unroll
        for (int c = 0; c < NF; ++c) row[c] = mi * ei[c];
#pragma unroll
        for (int c = 0; c < NF; ++c) row[10 + c] = mj * ej[c];
#pragma unroll
        for (int c = 0; c < NF; ++c) {
            float ctr = (float)(c + 1) * 0.7f;
            float df = ctr - dd;
            row[20 + c] = mi * fexp(-df * df);
        }
    }
    __syncthreads();

    // 1920 uint4 per batch; uint4 o covers f16 flat indices 8o..8o+7 where
    // idx = p*3072 + s*2 + e, p = o/384, s = 4*(o%384)+(kx>>1), e = kx&1.
    uint4* ob = xpair8 + (long)b * 1920;
    for (int o = t; o < 1920; o += 512) {
        unsigned p  = (unsigned)o / 384u;
        unsigned c4 = (unsigned)o - p * 384u;
        union { _Float16 h[8]; uint4 u; } pk;
#pragma unroll
        for (int kx = 0; kx < 8; ++kx) {
            unsigned s = 4u * c4 + (unsigned)(kx >> 1);
            unsigned e = (unsigned)(kx & 1);
            unsigned f = (2u * p + e) * 1536u + s;
            unsigned tt = f / 30u;            // compiler -> magic mul
            unsigned cc = f - tt * 30u;
            pk.h[kx] = (_Float16)lf[tt * 31u + cc];
        }
        ob[o] = pk.u;
    }
}

// One GRU step: reads hbuf16[PAR], writes hbuf16[PAR^1]. XQ = 5 uint4 chunk
// regs (4 steps of d-pairs); IDX in 0..3 selects the step's 32-bit word.
// All 60 dots are v_dot2_f32_f16 (2 f16 MACs/inst, FULL rate vs half-rate
// pk_fma_f32 -> halves the 240-cyc fp32 FLOP floor; f32 accumulate, no
// horizontal adds needed). Weights carry the log2e prescale (r/z x(-L),
// n x(-2L)) so each gate ends directly in exp2. Trailing wavefront fence
// replaces __syncthreads [R10: 576->420us].
#define STEP(PAR, XQ, IDX)                                                   \
    {                                                                        \
        const uint4* hv = (const uint4*)&hbuf16[PAR][half * 32];             \
        uint4 t0 = hv[0], t1 = hv[1], t2 = hv[2], t3 = hv[3];                \
        v2h hj[16];                                                          \
        __builtin_memcpy(&hj[0], &t0, 16);                                   \
        __builtin_memcpy(&hj[4], &t1, 16);                                   \
        __builtin_memcpy(&hj[8], &t2, 16);                                   \
        __builtin_memcpy(&hj[12], &t3, 16);                                  \
        v2h xc[5];                                                           \
        _Pragma("unroll")                                                    \
        for (int pp = 0; pp < 5; ++pp) {                                     \
            unsigned w = ((const unsigned*)&XQ[pp])[IDX];                    \
            __builtin_memcpy(&xc[pp], &w, 4);                                \
        }                                                                    \
        float ar = brf, az = bzf, ai = bif, ah = bhf;                        \
        _Pragma("unroll")                                                    \
        for (int j = 0; j < 15; ++j) {                                       \
            ar = __builtin_amdgcn_fdot2(whr[j], hj[j], ar, false);           \
            az = __builtin_amdgcn_fdot2(whz[j], hj[j], az, false);           \
            ah = __builtin_amdgcn_fdot2(whn[j], hj[j], ah, false);           \
        }                                                                    \
        _Pragma("unroll")                                                    \
        for (int d = 0; d < 5; ++d) {                                        \
            ar = __builtin_amdgcn_fdot2(wir[d], xc[d], ar, false);           \
            az = __builtin_amdgcn_fdot2(wiz[d], xc[d], az, false);           \
            ai = __builtin_amdgcn_fdot2(win[d], xc[d], ai, false);           \
        }                                                                    \
        float er = __builtin_amdgcn_exp2f(ar);                               \
        float ez = __builtin_amdgcn_exp2f(az);                               \
        float rg = frcp(1.0f + er);                                          \
        float zg = frcp(1.0f + ez);                                          \
        float ng =                                                           \
            2.0f * frcp(1.0f + __builtin_amdgcn_exp2f(ai + rg * ah)) - 1.0f; \
        h = ng + zg * (h - ng);                                              \
        hbuf16[(PAR) ^ 1][half * 32 + k] = (_Float16)h;                      \
        __builtin_amdgcn_fence(__ATOMIC_ACQ_REL, "wavefront");               \
    }

// Kernel 2: GRU recurrence — full-dot mapping (R9+), 2 batches per wave,
// 1024 single-wave blocks. Lane k (k<30) computes the complete gates for
// unit k of its half's batch. h state stays f32 in registers; LDS broadcast
// copy is f16 (quantization enters only via dot inputs, damped by z-gate).
// amdgpu_waves_per_eu(1,1) [R6/R9]: pressure ceiling = the 1 wave/SIMD the
// grid supplies -> weights stay arch-resident.
__attribute__((amdgpu_waves_per_eu(1, 1)))
__global__ void __launch_bounds__(64)
gru_kernel(const _Float16* __restrict__ xpair,
           const float* __restrict__ W_ih,   // [90,10]
           const float* __restrict__ W_hh,   // [90,30]
           const float* __restrict__ b_ih,   // [90]
           const float* __restrict__ b_hh,   // [90]
           const float* __restrict__ W_out,  // [1,30]
           const float* __restrict__ b_out,  // [1]
           float* __restrict__ out) {
    // Double-buffered f16 h: [buf][half*32 + k]; slots 30,31/62,63 written
    // by the k=30,31 lanes but never read (hj[15] unused).
    __shared__ __align__(16) _Float16 hbuf16[2][64];
    const int lane = threadIdx.x;
    const int half = lane >> 5;
    const int k    = lane & 31;
    const bool active = (k < HID);
    const int kk = active ? k : (HID - 1);
    const int b = blockIdx.x * 2 + half;

    const float SRZ = -LOG2E;          // sigmoid(x) = rcp(1+exp2(-L x))
    const float SN  = -2.0f * LOG2E;   // tanh(u) = 2 rcp(1+exp2(-2L u)) - 1

    // hh weights: 15 v2h (j-pairs) per gate, prescaled in f32 then RNE->f16.
    v2h whr[15], whz[15], whn[15];
    {
        const float2* Rr = (const float2*)&W_hh[(0 * HID + kk) * HID];
        const float2* Rz = (const float2*)&W_hh[(1 * HID + kk) * HID];
        const float2* Rn = (const float2*)&W_hh[(2 * HID + kk) * HID];
#pragma unroll
        for (int j = 0; j < 15; ++j) {
            float2 tr = Rr[j], tz = Rz[j], tn = Rn[j];
            whr[j] = (v2h){(_Float16)(tr.x * SRZ), (_Float16)(tr.y * SRZ)};
            whz[j] = (v2h){(_Float16)(tz.x * SRZ), (_Float16)(tz.y * SRZ)};
            whn[j] = (v2h){(_Float16)(tn.x * SN),  (_Float16)(tn.y * SN)};
        }
    }
    // ih weights: 5 v2h per gate (d-pairs match xpair layout).
    v2h wir[5], wiz[5], win[5];
    {
        const float2* Rr = (const float2*)&W_ih[(0 * HID + kk) * NF];
        const float2* Rz = (const float2*)&W_ih[(1 * HID + kk) * NF];
        const float2* Rn = (const float2*)&W_ih[(2 * HID + kk) * NF];
#pragma unroll
        for (int d = 0; d < 5; ++d) {
            float2 tr = Rr[d], tz = Rz[d], tn = Rn[d];
            wir[d] = (v2h){(_Float16)(tr.x * SRZ), (_Float16)(tr.y * SRZ)};
            wiz[d] = (v2h){(_Float16)(tz.x * SRZ), (_Float16)(tz.y * SRZ)};
            win[d] = (v2h){(_Float16)(tn.x * SN),  (_Float16)(tn.y * SN)};
        }
    }
    // Biases (prescaled, f32 — fdot2's accumulator seed).
    const float brf = SRZ * (b_ih[0 * HID + kk] + b_hh[0 * HID + kk]);
    const float bzf = SRZ * (b_ih[1 * HID + kk] + b_hh[1 * HID + kk]);
    const float bif = SN * b_ih[2 * HID + kk];  // n biases stay split:
    const float bhf = SN * b_hh[2 * HID + kk];  // n uses ai + rg*ah

    // 5 chunk streams: xa[p][c] = uint4 = d-pair (2p,2p+1), steps 4c..4c+3
    const _Float16* xb = xpair + (long)b * FEAT_PER_B;
    const uint4* xa[5];
#pragma unroll
    for (int p = 0; p < 5; ++p) xa[p] = (const uint4*)(xb + p * 3072);

    hbuf16[0][lane] = (_Float16)0.0f;
    hbuf16[1][lane] = (_Float16)0.0f;
    __builtin_amdgcn_fence(__ATOMIC_ACQ_REL, "wavefront");

    float h = 0.0f;
    uint4 xq0[5], xq1[5];
#pragma unroll
    for (int p = 0; p < 5; ++p) xq0[p] = xa[p][0];

    // 384 chunks of 4 steps; prefetch distance 1 (clamped at the tail)
    for (int c = 0; c < 384; ++c) {
        const int cn = (c + 1 < 384) ? (c + 1) : c;
#pragma unroll
        for (int p = 0; p < 5; ++p) xq1[p] = xa[p][cn];
        STEP(0, xq0, 0);
        STEP(1, xq0, 1);
        STEP(0, xq0, 2);
        STEP(1, xq0, 3);
#pragma unroll
        for (int p = 0; p < 5; ++p) xq0[p] = xq1[p];
    }

    // out[b] = relu(h . W_out + b_out), reduced within each 32-lane half
    float v = active ? h * W_out[kk] : 0.0f;
#pragma unroll
    for (int off = 16; off; off >>= 1) v += __shfl_xor(v, off, 32);
    if (k == 0) {
        float o = v + b_out[0];
        out[b] = o > 0.0f ? o : 0.0f;
    }
}

extern "C" void kernel_launch(void* const* d_in, const int* in_sizes, int n_in,
                              void* d_out, int out_size, void* d_ws, size_t ws_size,
                              hipStream_t stream) {
    const int* atom_i   = (const int*)d_in[0];
    const int* atom_j   = (const int*)d_in[1];
    const float* dist   = (const float*)d_in[2];
    const float* emb    = (const float*)d_in[3];
    const float* W_ih   = (const float*)d_in[4];
    const float* W_hh   = (const float*)d_in[5];
    const float* b_ih   = (const float*)d_in[6];
    const float* b_hh   = (const float*)d_in[7];
    const float* W_out  = (const float*)d_in[8];
    const float* b_out  = (const float*)d_in[9];
    float* out = (float*)d_out;
    _Float16* xpair = (_Float16*)d_ws;   // 62,914,560 B

    feat_kernel<<<BATCH, 512, 0, stream>>>(atom_i, atom_j, dist, emb,
                                           (uint4*)xpair);
    gru_kernel<<<BATCH / 2, 64, 0, stream>>>(xpair, W_ih, W_hh, b_ih, b_hh,
                                             W_out, b_out, out);
}